// Round 1
// 290.562 us; speedup vs baseline: 1.1523x; 1.1523x over previous
//
#include <hip/hip_runtime.h>
#include <hip/hip_bf16.h>

#define K_DIM 4096
#define N_DIM 4096
#define M_DIM 4096

typedef __attribute__((ext_vector_type(8)))  short bf16x8;    // 8 bf16, 4 VGPRs
typedef __attribute__((ext_vector_type(4)))  float f32x4;     // 16x16 MFMA acc
typedef __attribute__((ext_vector_type(16))) float f32x16;    // 32x32 MFMA acc (fallback)
typedef __attribute__((ext_vector_type(8)))  unsigned short u16x8;

// ---------- fp32 -> bf16 (round-to-nearest-even) ----------
__device__ __forceinline__ unsigned short f2bf(float f) {
    union { float f; unsigned int u; } v; v.f = f;
    unsigned int u = v.u;
    return (unsigned short)((u + 0x7fffu + ((u >> 16) & 1u)) >> 16);
}

// ---------- fused convert: x and W in one launch ----------
__global__ void cvt2_f32_to_bf16(const float* __restrict__ x,
                                 const float* __restrict__ W,
                                 unsigned short* __restrict__ xb,
                                 unsigned short* __restrict__ wb,
                                 int blocks_each) {
    int b = blockIdx.x;
    const float* src = x;
    unsigned short* dst = xb;
    if (b >= blocks_each) { b -= blocks_each; src = W; dst = wb; }
    const int i = (b * 256 + threadIdx.x) * 8;
    float4 f0 = *(const float4*)(src + i);
    float4 f1 = *(const float4*)(src + i + 4);
    u16x8 o;
    o[0] = f2bf(f0.x); o[1] = f2bf(f0.y); o[2] = f2bf(f0.z); o[3] = f2bf(f0.w);
    o[4] = f2bf(f1.x); o[5] = f2bf(f1.y); o[6] = f2bf(f1.z); o[7] = f2bf(f1.w);
    *(u16x8*)(dst + i) = o;
}

// ---------- async global->LDS, 16B per lane (dest = wave-uniform base + lane*16) ----------
__device__ __forceinline__ void gl_lds16(const void* g, void* l) {
    __builtin_amdgcn_global_load_lds(
        (const __attribute__((address_space(1))) void*)g,
        (__attribute__((address_space(3))) void*)l,
        16, 0, 0);
}

// ============================================================================
// 256x256 tile, BK=64, 8-wave, 8-phase counted-vmcnt schedule (m201 template).
//   LDS short-offsets: [buf:+32768][A:+0 / B:+16384][khalf:+8192]; each region
//   = 256 rows x 32 bf16 (one K-half of one operand tile), linear row-major,
//   granule (16B) slot q holds global granule q ^ ((row>>1)&3)  (2-way = free).
//   Phase = {ds_reads | 1 half-tile global_load_lds} barrier {16 MFMA w/
//   setprio} barrier.  vmcnt(6) once per K-tile (3 half-tiles in flight).
// ============================================================================
__global__ __launch_bounds__(512, 2) void gemm256(
    const unsigned short* __restrict__ A,   // [M,K] bf16
    const unsigned short* __restrict__ B,   // [N,K] bf16
    const float* __restrict__ bias, float* __restrict__ C) {

    __shared__ __align__(16) unsigned short sh[65536];   // 128 KiB

    const int tid  = threadIdx.x;
    const int wave = tid >> 6;
    const int lane = tid & 63;
    const int l16  = lane & 15;
    const int gq   = lane >> 4;        // k-granule 0..3
    const int wm   = wave >> 2;        // 0..1  (M row of wave grid)
    const int wn   = wave & 3;         // 0..3  (N col of wave grid)

    // XCD swizzle: 256 blocks over 8 XCDs; per-XCD 4x8 patch of 256^2 tiles.
    const int bid = blockIdx.x;
    const int xcd = bid & 7;
    const int idx = bid >> 3;                          // 0..31
    const int mt  = ((xcd >> 1) << 2) + (idx >> 3);    // 0..15
    const int nt  = ((xcd & 1) << 3) + (idx & 7);      // 0..15
    const size_t bm = (size_t)mt << 8;
    const size_t bn = (size_t)nt << 8;

    // ---- staging geometry: 512 thr x 16B = 8KB -> 2 loads per 16KB half-tile
    const int srow  = tid >> 2;                              // 0..127
    const int sg8   = ((tid & 3) ^ ((tid >> 3) & 3)) << 3;   // inverse-swizzled src granule
    const int wslot = wave << 9;                             // wave*512 shorts

    const unsigned short* Abase = A + bm * K_DIM;
    const unsigned short* Bbase = B + bn * K_DIM;

    auto stage = [&](const unsigned short* __restrict__ P, int dstbase, int kelem) {
        const unsigned short* s0 = P + (size_t)srow * K_DIM + kelem + sg8;
        gl_lds16(s0,                        &sh[dstbase + wslot]);
        gl_lds16(s0 + (size_t)128 * K_DIM,  &sh[dstbase + 4096 + wslot]);
    };

    // ---- read-side: frag row = base + l16; swizzle term is frag-invariant
    const int koff = (gq ^ ((l16 >> 1) & 3)) << 3;           // shorts
    const int aoff = ((wm << 7) + l16) * 32 + koff;
    const int boff = ((wn << 6) + l16) * 32 + koff;

    f32x4 acc[8][4] = {};   // 8 m-frags x 4 n-frags (128 VGPR)

    // ---- prologue: tile0 (4 half-tiles) + tile1 first 3; keep last 3 in flight
    stage(Abase, 0,             0);     // A k0 (t0)
    stage(Bbase, 16384,         0);     // B k0 (t0)
    stage(Abase, 8192,          32);    // A k1 (t0)
    stage(Bbase, 24576,         32);    // B k1 (t0)
    stage(Bbase, 32768 + 16384, 64);    // B k0 (t1)
    stage(Abase, 32768 + 0,     64);    // A k0 (t1)
    stage(Bbase, 32768 + 24576, 96);    // B k1 (t1)
    asm volatile("s_waitcnt vmcnt(6)" ::: "memory");   // tile0 landed
    __builtin_amdgcn_s_barrier();

#define PHASE_MFMA(FOFF)                                                      \
    __builtin_amdgcn_s_setprio(1);                                            \
    _Pragma("unroll")                                                         \
    for (int f = 0; f < 4; f++)                                               \
        _Pragma("unroll")                                                     \
        for (int n = 0; n < 4; n++)                                           \
            acc[f + FOFF][n] = __builtin_amdgcn_mfma_f32_16x16x32_bf16(       \
                a[f], b[n], acc[f + FOFF][n], 0, 0, 0);                       \
    __builtin_amdgcn_s_setprio(0);

    // stmode: 0 = steady state, 1 = stage only A-k1(t+1) + drain, 2 = no stage
    auto ktile = [&](int t, int stmode) {
        const int buf  = (t & 1) << 15;
        const int obuf = buf ^ 32768;
        const int kA1  = (t + 1) * 64 + 32;
        const int k2   = (t + 2) * 64;
        const int A0 = buf, A1 = buf + 8192, B0 = buf + 16384, B1 = buf + 24576;
        bf16x8 a[4], b[4];

        // ---- phase 1: (m-half 0, k-half 0); stage A-k1(t+1) -> other buffer
#pragma unroll
        for (int f = 0; f < 4; f++) a[f] = *(const bf16x8*)&sh[A0 + aoff + f * 512];
#pragma unroll
        for (int n = 0; n < 4; n++) b[n] = *(const bf16x8*)&sh[B0 + boff + n * 512];
        if (stmode <= 1) stage(Abase, obuf + 8192, kA1);
        __builtin_amdgcn_s_barrier();
        PHASE_MFMA(0)
        __builtin_amdgcn_s_barrier();

        // ---- phase 2: (m-half 1, k-half 0); B regs reused; stage B-k0(t+2)
#pragma unroll
        for (int f = 0; f < 4; f++) a[f] = *(const bf16x8*)&sh[A0 + aoff + (f + 4) * 512];
        if (stmode == 0) stage(Bbase, B0, k2);      // B0(t) last read in ph1
        __builtin_amdgcn_s_barrier();
        PHASE_MFMA(4)
        __builtin_amdgcn_s_barrier();

        // ---- phase 3: (m-half 0, k-half 1); stage A-k0(t+2)
#pragma unroll
        for (int f = 0; f < 4; f++) a[f] = *(const bf16x8*)&sh[A1 + aoff + f * 512];
#pragma unroll
        for (int n = 0; n < 4; n++) b[n] = *(const bf16x8*)&sh[B1 + boff + n * 512];
        if (stmode == 0) stage(Abase, A0, k2);      // A0(t) last read in ph2
        __builtin_amdgcn_s_barrier();
        PHASE_MFMA(0)
        __builtin_amdgcn_s_barrier();

        // ---- phase 4: (m-half 1, k-half 1); stage B-k1(t+2); counted vmcnt
#pragma unroll
        for (int f = 0; f < 4; f++) a[f] = *(const bf16x8*)&sh[A1 + aoff + (f + 4) * 512];
        if (stmode == 0) {
            stage(Bbase, B1, k2 + 32);              // B1(t) last read in ph3
            asm volatile("s_waitcnt vmcnt(6)" ::: "memory");  // tile t+1 landed
        } else if (stmode == 1) {
            asm volatile("s_waitcnt vmcnt(0)" ::: "memory");  // drain tail
        }
        __builtin_amdgcn_s_barrier();
        PHASE_MFMA(4)
        __builtin_amdgcn_s_barrier();
    };

    for (int t = 0; t < 62; ++t) ktile(t, 0);
    ktile(62, 1);
    ktile(63, 2);
#undef PHASE_MFMA

    // ---- epilogue: 16x16 C/D layout: col = lane&15, row = (lane>>4)*4 + reg
    const size_t row0 = bm + (wm << 7) + (gq << 2);
    const size_t col0 = bn + (wn << 6) + l16;
#pragma unroll
    for (int n = 0; n < 4; n++) {
        const size_t col = col0 + n * 16;
        const float bv = bias[col];
#pragma unroll
        for (int f = 0; f < 8; f++) {
            const size_t r = row0 + f * 16;
#pragma unroll
            for (int j = 0; j < 4; j++)
                C[(r + j) * N_DIM + col] = acc[f][n][j] + bv;
        }
    }
}

// ============================================================================
// Fallback (no workspace): previous-session 128x128 fp32-input kernel, verbatim.
// ============================================================================
#define BM 128
#define BN 128
#define BK 32

__global__ __launch_bounds__(256) void gemm_bt_f32(
    const float* __restrict__ Aptr, const float* __restrict__ Bptr,
    const float* __restrict__ bias, float* __restrict__ C) {

    __shared__ __align__(16) unsigned short As[BM * BK];
    __shared__ __align__(16) unsigned short Bs[BN * BK];

    const int tid  = threadIdx.x;
    const int wave = tid >> 6;
    const int lane = tid & 63;
    const int r32  = lane & 31;
    const int hi   = lane >> 5;

    const int bid = blockIdx.x;
    const int xcd = bid & 7;
    const int idx = bid >> 3;
    const int mt  = ((xcd & 1) << 4) + (idx & 15);
    const int nt  = (((xcd >> 1) & 3) << 3) + (idx >> 4);
    const int bm  = mt * BM;
    const int bn  = nt * BN;

    const int wm = (wave & 1) * 64;
    const int wn = (wave >> 1) * 64;

    f32x16 acc[2][2] = {};
    const int sw = (r32 >> 1) & 3;

    for (int k0 = 0; k0 < K_DIM; k0 += BK) {
        __syncthreads();
        {
            const int r  = tid >> 1;
            const int q0 = (tid & 1) << 1;
            const int s  = (r >> 1) & 3;
            {
                const float* sp = &Aptr[(size_t)(bm + r) * K_DIM + k0 + (q0 << 3)];
                float4 f0 = *(const float4*)(sp + 0);
                float4 f1 = *(const float4*)(sp + 4);
                float4 f2 = *(const float4*)(sp + 8);
                float4 f3 = *(const float4*)(sp + 12);
                u16x8 o0, o1;
                o0[0]=f2bf(f0.x); o0[1]=f2bf(f0.y); o0[2]=f2bf(f0.z); o0[3]=f2bf(f0.w);
                o0[4]=f2bf(f1.x); o0[5]=f2bf(f1.y); o0[6]=f2bf(f1.z); o0[7]=f2bf(f1.w);
                o1[0]=f2bf(f2.x); o1[1]=f2bf(f2.y); o1[2]=f2bf(f2.z); o1[3]=f2bf(f2.w);
                o1[4]=f2bf(f3.x); o1[5]=f2bf(f3.y); o1[6]=f2bf(f3.z); o1[7]=f2bf(f3.w);
                *(u16x8*)&As[r * BK + ((q0 ^ s) << 3)]       = o0;
                *(u16x8*)&As[r * BK + (((q0 + 1) ^ s) << 3)] = o1;
            }
            {
                const float* sp = &Bptr[(size_t)(bn + r) * K_DIM + k0 + (q0 << 3)];
                float4 f0 = *(const float4*)(sp + 0);
                float4 f1 = *(const float4*)(sp + 4);
                float4 f2 = *(const float4*)(sp + 8);
                float4 f3 = *(const float4*)(sp + 12);
                u16x8 o0, o1;
                o0[0]=f2bf(f0.x); o0[1]=f2bf(f0.y); o0[2]=f2bf(f0.z); o0[3]=f2bf(f0.w);
                o0[4]=f2bf(f1.x); o0[5]=f2bf(f1.y); o0[6]=f2bf(f1.z); o0[7]=f2bf(f1.w);
                o1[0]=f2bf(f2.x); o1[1]=f2bf(f2.y); o1[2]=f2bf(f2.z); o1[3]=f2bf(f2.w);
                o1[4]=f2bf(f3.x); o1[5]=f2bf(f3.y); o1[6]=f2bf(f3.z); o1[7]=f2bf(f3.w);
                *(u16x8*)&Bs[r * BK + ((q0 ^ s) << 3)]       = o0;
                *(u16x8*)&Bs[r * BK + (((q0 + 1) ^ s) << 3)] = o1;
            }
        }
        __syncthreads();

        bf16x8 af[2][2], bfv[2][2];
#pragma unroll
        for (int t = 0; t < 2; t++)
#pragma unroll
            for (int h = 0; h < 2; h++) {
                const int koffl = (((hi + 2 * h) ^ sw)) << 3;
                af[t][h]  = *(const bf16x8*)&As[(wm + t * 32 + r32) * BK + koffl];
                bfv[t][h] = *(const bf16x8*)&Bs[(wn + t * 32 + r32) * BK + koffl];
            }
#pragma unroll
        for (int h = 0; h < 2; h++)
#pragma unroll
            for (int i = 0; i < 2; i++)
#pragma unroll
                for (int j = 0; j < 2; j++)
                    acc[i][j] = __builtin_amdgcn_mfma_f32_32x32x16_bf16(
                        af[i][h], bfv[j][h], acc[i][j], 0, 0, 0);
    }

#pragma unroll
    for (int i = 0; i < 2; i++) {
        const int rowb = bm + wm + i * 32 + 4 * hi;
#pragma unroll
        for (int j = 0; j < 2; j++) {
            const int col = bn + wn + j * 32 + r32;
            const float bv = bias[col];
#pragma unroll
            for (int reg = 0; reg < 16; reg++) {
                const int row = rowb + (reg & 3) + 8 * (reg >> 2);
                C[(size_t)row * N_DIM + col] = acc[i][j][reg] + bv;
            }
        }
    }
}

extern "C" void kernel_launch(void* const* d_in, const int* in_sizes, int n_in,
                              void* d_out, int out_size, void* d_ws, size_t ws_size,
                              hipStream_t stream) {
    const float* x = (const float*)d_in[0];   // [M, K]
    const float* W = (const float*)d_in[1];   // [N, K]
    const float* b = (const float*)d_in[2];   // [N]
    float* out = (float*)d_out;               // [M, N]

    const size_t elems = (size_t)M_DIM * K_DIM;
    const size_t need  = 2 * elems * sizeof(unsigned short);  // 64 MB

    if (ws_size >= need) {
        unsigned short* xb = (unsigned short*)d_ws;
        unsigned short* wb = xb + elems;
        const int blocks_each = (int)(elems / (256 * 8));     // 8192
        cvt2_f32_to_bf16<<<2 * blocks_each, 256, 0, stream>>>(x, W, xb, wb, blocks_each);
        dim3 grid((M_DIM / 256) * (N_DIM / 256));             // 256 blocks = 1/CU
        gemm256<<<grid, dim3(512), 0, stream>>>(xb, wb, b, out);
    } else {
        dim3 grid((M_DIM / BM) * (N_DIM / BN));
        gemm_bt_f32<<<grid, dim3(256), 0, stream>>>(x, W, b, out);
    }
}

// Round 2
// 287.256 us; speedup vs baseline: 1.1655x; 1.0115x over previous
//
#include <hip/hip_runtime.h>
#include <hip/hip_bf16.h>

#define K_DIM 4096
#define N_DIM 4096
#define M_DIM 4096

typedef __attribute__((ext_vector_type(8)))  short bf16x8;    // 8 bf16, 4 VGPRs
typedef __attribute__((ext_vector_type(4)))  float f32x4;     // 16x16 MFMA acc
typedef __attribute__((ext_vector_type(16))) float f32x16;    // 32x32 MFMA acc (fallback)
typedef __attribute__((ext_vector_type(8)))  unsigned short u16x8;

// ---------- fp32 -> bf16 (round-to-nearest-even) ----------
__device__ __forceinline__ unsigned short f2bf(float f) {
    union { float f; unsigned int u; } v; v.f = f;
    unsigned int u = v.u;
    return (unsigned short)((u + 0x7fffu + ((u >> 16) & 1u)) >> 16);
}

// ---------- fused convert: x and W in one launch ----------
__global__ void cvt2_f32_to_bf16(const float* __restrict__ x,
                                 const float* __restrict__ W,
                                 unsigned short* __restrict__ xb,
                                 unsigned short* __restrict__ wb,
                                 int blocks_each) {
    int b = blockIdx.x;
    const float* src = x;
    unsigned short* dst = xb;
    if (b >= blocks_each) { b -= blocks_each; src = W; dst = wb; }
    const int i = (b * 256 + threadIdx.x) * 8;
    float4 f0 = *(const float4*)(src + i);
    float4 f1 = *(const float4*)(src + i + 4);
    u16x8 o;
    o[0] = f2bf(f0.x); o[1] = f2bf(f0.y); o[2] = f2bf(f0.z); o[3] = f2bf(f0.w);
    o[4] = f2bf(f1.x); o[5] = f2bf(f1.y); o[6] = f2bf(f1.z); o[7] = f2bf(f1.w);
    *(u16x8*)(dst + i) = o;
}

// ---------- async global->LDS, 16B per lane (dest = wave-uniform base + lane*16) ----------
__device__ __forceinline__ void gl_lds16(const void* g, void* l) {
    __builtin_amdgcn_global_load_lds(
        (const __attribute__((address_space(1))) void*)g,
        (__attribute__((address_space(3))) void*)l,
        16, 0, 0);
}

// ============================================================================
// 256x256 tile, BK=64, 8-wave, 4-phase-per-K-tile counted-vmcnt schedule.
// V2 vs V1: ONE barrier per phase (at phase end) instead of two.
//   Safety invariant: every stage() targets a region whose last ds_read was
//   consumed (wave-local lgkm wait before that wave's MFMAs) before the
//   previous barrier -> >=1 full barrier between consumption and overwrite.
//   Removing the pre-MFMA barrier lets (a) the compiler run MFMAs under
//   counted lgkmcnt while later reads drain, (b) waves slip so one wave's
//   MFMA covers another's LDS drain (LDS pipe stays busy; setprio arbitrates).
// K-loop unrolled by buffer pairs -> all LDS bases compile-time constants.
//   vmcnt(6) once per K-tile (3 half-tiles = 6 loads in flight), never 0
//   in the main loop.
// ============================================================================
__global__ __launch_bounds__(512, 2) void gemm256(
    const unsigned short* __restrict__ A,   // [M,K] bf16
    const unsigned short* __restrict__ B,   // [N,K] bf16
    const float* __restrict__ bias, float* __restrict__ C) {

    __shared__ __align__(16) unsigned short sh[65536];   // 128 KiB

    const int tid  = threadIdx.x;
    const int wave = tid >> 6;
    const int lane = tid & 63;
    const int l16  = lane & 15;
    const int gq   = lane >> 4;        // k-granule 0..3
    const int wm   = wave >> 2;        // 0..1  (M row of wave grid)
    const int wn   = wave & 3;         // 0..3  (N col of wave grid)

    // XCD swizzle: 256 blocks over 8 XCDs; per-XCD 4x8 patch of 256^2 tiles.
    const int bid = blockIdx.x;
    const int xcd = bid & 7;
    const int idx = bid >> 3;                          // 0..31
    const int mt  = ((xcd >> 1) << 2) + (idx >> 3);    // 0..15
    const int nt  = ((xcd & 1) << 3) + (idx & 7);      // 0..15
    const size_t bm = (size_t)mt << 8;
    const size_t bn = (size_t)nt << 8;

    // ---- staging geometry: 512 thr x 16B = 8KB -> 2 loads per 16KB half-tile
    const int srow  = tid >> 2;                              // 0..127
    const int sg8   = ((tid & 3) ^ ((tid >> 3) & 3)) << 3;   // inverse-swizzled src granule
    const int wslot = wave << 9;                             // wave*512 shorts

    const unsigned short* Abase = A + bm * K_DIM;
    const unsigned short* Bbase = B + bn * K_DIM;

    auto stage = [&](const unsigned short* __restrict__ P, int dstbase, int kelem) {
        const unsigned short* s0 = P + (size_t)srow * K_DIM + kelem + sg8;
        gl_lds16(s0,                        &sh[dstbase + wslot]);
        gl_lds16(s0 + (size_t)128 * K_DIM,  &sh[dstbase + 4096 + wslot]);
    };

    // ---- read-side: frag row = base + l16; swizzle term is frag-invariant
    // bank map: lane -> (16*l16 + 4*(gq^((l16>>1)&3))) mod 32 -> exactly 2
    // lanes/bank (free per m136); measured 0 SQ_LDS_BANK_CONFLICT in R1.
    const int koff = (gq ^ ((l16 >> 1) & 3)) << 3;           // shorts
    const int aoff = ((wm << 7) + l16) * 32 + koff;
    const int boff = ((wn << 6) + l16) * 32 + koff;

    f32x4 acc[8][4] = {};   // 8 m-frags x 4 n-frags (128 acc regs)

    // ---- prologue: tile0 (4 half-tiles) + tile1 first 3; keep last 3 in flight
    stage(Abase, 0,             0);     // A k0 (t0)
    stage(Bbase, 16384,         0);     // B k0 (t0)
    stage(Abase, 8192,          32);    // A k1 (t0)
    stage(Bbase, 24576,         32);    // B k1 (t0)
    stage(Bbase, 32768 + 16384, 64);    // B k0 (t1)
    stage(Abase, 32768 + 0,     64);    // A k0 (t1)
    stage(Bbase, 32768 + 24576, 96);    // B k1 (t1)
    asm volatile("s_waitcnt vmcnt(6)" ::: "memory");   // tile0 landed
    __builtin_amdgcn_s_barrier();

#define PHASE_MFMA(FOFF)                                                      \
    __builtin_amdgcn_s_setprio(1);                                            \
    _Pragma("unroll")                                                         \
    for (int f = 0; f < 4; f++)                                               \
        _Pragma("unroll")                                                     \
        for (int n = 0; n < 4; n++)                                           \
            acc[f + FOFF][n] = __builtin_amdgcn_mfma_f32_16x16x32_bf16(       \
                a[f], b[n], acc[f + FOFF][n], 0, 0, 0);                       \
    __builtin_amdgcn_s_setprio(0);

    // stmode: 0 = steady state, 1 = stage only A-k1(t+1) + drain, 2 = no stage
    // buf is a literal at every call site -> static LDS bases after inlining.
    auto ktile = [&](const int buf, const int t, const int stmode) {
        const int obuf = buf ^ 32768;
        const int kA1  = (t + 1) * 64 + 32;
        const int k2   = (t + 2) * 64;
        const int A0 = buf, A1 = buf + 8192, B0 = buf + 16384, B1 = buf + 24576;
        bf16x8 a[4], b[4];

        // ---- phase 1: (m-half 0, k-half 0); stage A-k1(t+1) -> other buffer
#pragma unroll
        for (int f = 0; f < 4; f++) a[f] = *(const bf16x8*)&sh[A0 + aoff + f * 512];
#pragma unroll
        for (int n = 0; n < 4; n++) b[n] = *(const bf16x8*)&sh[B0 + boff + n * 512];
        if (stmode <= 1) stage(Abase, obuf + 8192, kA1);
        PHASE_MFMA(0)
        __builtin_amdgcn_s_barrier();

        // ---- phase 2: (m-half 1, k-half 0); B regs reused; stage B-k0(t+2)
        //      (B0(t) consumed before phase-1 barrier by every wave)
#pragma unroll
        for (int f = 0; f < 4; f++) a[f] = *(const bf16x8*)&sh[A0 + aoff + (f + 4) * 512];
        if (stmode == 0) stage(Bbase, B0, k2);
        PHASE_MFMA(4)
        __builtin_amdgcn_s_barrier();

        // ---- phase 3: (m-half 0, k-half 1); stage A-k0(t+2)
#pragma unroll
        for (int f = 0; f < 4; f++) a[f] = *(const bf16x8*)&sh[A1 + aoff + f * 512];
#pragma unroll
        for (int n = 0; n < 4; n++) b[n] = *(const bf16x8*)&sh[B1 + boff + n * 512];
        if (stmode == 0) stage(Abase, A0, k2);
        PHASE_MFMA(0)
        __builtin_amdgcn_s_barrier();

        // ---- phase 4: (m-half 1, k-half 1); stage B-k1(t+2); counted vmcnt
#pragma unroll
        for (int f = 0; f < 4; f++) a[f] = *(const bf16x8*)&sh[A1 + aoff + (f + 4) * 512];
        if (stmode == 0) {
            stage(Bbase, B1, k2 + 32);
            asm volatile("s_waitcnt vmcnt(6)" ::: "memory");  // tile t+1 landed
        } else if (stmode == 1) {
            asm volatile("s_waitcnt vmcnt(0)" ::: "memory");  // drain tail
        }
        PHASE_MFMA(4)
        __builtin_amdgcn_s_barrier();
    };

    for (int t = 0; t < 62; t += 2) {
        ktile(0,     t,     0);
        ktile(32768, t + 1, 0);
    }
    ktile(0,     62, 1);
    ktile(32768, 63, 2);
#undef PHASE_MFMA

    // ---- epilogue: 16x16 C/D layout: col = lane&15, row = (lane>>4)*4 + reg
    const size_t row0 = bm + (wm << 7) + (gq << 2);
    const size_t col0 = bn + (wn << 6) + l16;
#pragma unroll
    for (int n = 0; n < 4; n++) {
        const size_t col = col0 + n * 16;
        const float bv = bias[col];
#pragma unroll
        for (int f = 0; f < 8; f++) {
            const size_t r = row0 + f * 16;
#pragma unroll
            for (int j = 0; j < 4; j++)
                C[(r + j) * N_DIM + col] = acc[f][n][j] + bv;
        }
    }
}

// ============================================================================
// Fallback (no workspace): previous-session 128x128 fp32-input kernel, verbatim.
// ============================================================================
#define BM 128
#define BN 128
#define BK 32

__global__ __launch_bounds__(256) void gemm_bt_f32(
    const float* __restrict__ Aptr, const float* __restrict__ Bptr,
    const float* __restrict__ bias, float* __restrict__ C) {

    __shared__ __align__(16) unsigned short As[BM * BK];
    __shared__ __align__(16) unsigned short Bs[BN * BK];

    const int tid  = threadIdx.x;
    const int wave = tid >> 6;
    const int lane = tid & 63;
    const int r32  = lane & 31;
    const int hi   = lane >> 5;

    const int bid = blockIdx.x;
    const int xcd = bid & 7;
    const int idx = bid >> 3;
    const int mt  = ((xcd & 1) << 4) + (idx & 15);
    const int nt  = (((xcd >> 1) & 3) << 3) + (idx >> 4);
    const int bm  = mt * BM;
    const int bn  = nt * BN;

    const int wm = (wave & 1) * 64;
    const int wn = (wave >> 1) * 64;

    f32x16 acc[2][2] = {};
    const int sw = (r32 >> 1) & 3;

    for (int k0 = 0; k0 < K_DIM; k0 += BK) {
        __syncthreads();
        {
            const int r  = tid >> 1;
            const int q0 = (tid & 1) << 1;
            const int s  = (r >> 1) & 3;
            {
                const float* sp = &Aptr[(size_t)(bm + r) * K_DIM + k0 + (q0 << 3)];
                float4 f0 = *(const float4*)(sp + 0);
                float4 f1 = *(const float4*)(sp + 4);
                float4 f2 = *(const float4*)(sp + 8);
                float4 f3 = *(const float4*)(sp + 12);
                u16x8 o0, o1;
                o0[0]=f2bf(f0.x); o0[1]=f2bf(f0.y); o0[2]=f2bf(f0.z); o0[3]=f2bf(f0.w);
                o0[4]=f2bf(f1.x); o0[5]=f2bf(f1.y); o0[6]=f2bf(f1.z); o0[7]=f2bf(f1.w);
                o1[0]=f2bf(f2.x); o1[1]=f2bf(f2.y); o1[2]=f2bf(f2.z); o1[3]=f2bf(f2.w);
                o1[4]=f2bf(f3.x); o1[5]=f2bf(f3.y); o1[6]=f2bf(f3.z); o1[7]=f2bf(f3.w);
                *(u16x8*)&As[r * BK + ((q0 ^ s) << 3)]       = o0;
                *(u16x8*)&As[r * BK + (((q0 + 1) ^ s) << 3)] = o1;
            }
            {
                const float* sp = &Bptr[(size_t)(bn + r) * K_DIM + k0 + (q0 << 3)];
                float4 f0 = *(const float4*)(sp + 0);
                float4 f1 = *(const float4*)(sp + 4);
                float4 f2 = *(const float4*)(sp + 8);
                float4 f3 = *(const float4*)(sp + 12);
                u16x8 o0, o1;
                o0[0]=f2bf(f0.x); o0[1]=f2bf(f0.y); o0[2]=f2bf(f0.z); o0[3]=f2bf(f0.w);
                o0[4]=f2bf(f1.x); o0[5]=f2bf(f1.y); o0[6]=f2bf(f1.z); o0[7]=f2bf(f1.w);
                o1[0]=f2bf(f2.x); o1[1]=f2bf(f2.y); o1[2]=f2bf(f2.z); o1[3]=f2bf(f2.w);
                o1[4]=f2bf(f3.x); o1[5]=f2bf(f3.y); o1[6]=f2bf(f3.z); o1[7]=f2bf(f3.w);
                *(u16x8*)&Bs[r * BK + ((q0 ^ s) << 3)]       = o0;
                *(u16x8*)&Bs[r * BK + (((q0 + 1) ^ s) << 3)] = o1;
            }
        }
        __syncthreads();

        bf16x8 af[2][2], bfv[2][2];
#pragma unroll
        for (int t = 0; t < 2; t++)
#pragma unroll
            for (int h = 0; h < 2; h++) {
                const int koffl = (((hi + 2 * h) ^ sw)) << 3;
                af[t][h]  = *(const bf16x8*)&As[(wm + t * 32 + r32) * BK + koffl];
                bfv[t][h] = *(const bf16x8*)&Bs[(wn + t * 32 + r32) * BK + koffl];
            }
#pragma unroll
        for (int h = 0; h < 2; h++)
#pragma unroll
            for (int i = 0; i < 2; i++)
#pragma unroll
                for (int j = 0; j < 2; j++)
                    acc[i][j] = __builtin_amdgcn_mfma_f32_32x32x16_bf16(
                        af[i][h], bfv[j][h], acc[i][j], 0, 0, 0);
    }

#pragma unroll
    for (int i = 0; i < 2; i++) {
        const int rowb = bm + wm + i * 32 + 4 * hi;
#pragma unroll
        for (int j = 0; j < 2; j++) {
            const int col = bn + wn + j * 32 + r32;
            const float bv = bias[col];
#pragma unroll
            for (int reg = 0; reg < 16; reg++) {
                const int row = rowb + (reg & 3) + 8 * (reg >> 2);
                C[(size_t)row * N_DIM + col] = acc[i][j][reg] + bv;
            }
        }
    }
}

extern "C" void kernel_launch(void* const* d_in, const int* in_sizes, int n_in,
                              void* d_out, int out_size, void* d_ws, size_t ws_size,
                              hipStream_t stream) {
    const float* x = (const float*)d_in[0];   // [M, K]
    const float* W = (const float*)d_in[1];   // [N, K]
    const float* b = (const float*)d_in[2];   // [N]
    float* out = (float*)d_out;               // [M, N]

    const size_t elems = (size_t)M_DIM * K_DIM;
    const size_t need  = 2 * elems * sizeof(unsigned short);  // 64 MB

    if (ws_size >= need) {
        unsigned short* xb = (unsigned short*)d_ws;
        unsigned short* wb = xb + elems;
        const int blocks_each = (int)(elems / (256 * 8));     // 8192
        cvt2_f32_to_bf16<<<2 * blocks_each, 256, 0, stream>>>(x, W, xb, wb, blocks_each);
        dim3 grid((M_DIM / 256) * (N_DIM / 256));             // 256 blocks = 1/CU
        gemm256<<<grid, dim3(512), 0, stream>>>(xb, wb, b, out);
    } else {
        dim3 grid((M_DIM / BM) * (N_DIM / BN));
        gemm_bt_f32<<<grid, dim3(256), 0, stream>>>(x, W, b, out);
    }
}